// Round 2
// baseline (720.148 us; speedup 1.0000x reference)
//
#include <hip/hip_runtime.h>
#include <hip/hip_bf16.h>
#include <cstdint>
#include <cstddef>

typedef __hip_bfloat16 bf16;
typedef short bf16x8 __attribute__((ext_vector_type(8)));
typedef float f32x4 __attribute__((ext_vector_type(4)));

#define MFMA(a, b, c) __builtin_amdgcn_mfma_f32_16x16x32_bf16((a), (b), (c), 0, 0, 0)

// ---------------------------------------------------------------------------
// K0: transpose weights f32 -> bf16: dst[n*K+k] = src[k*N+n]
// ---------------------------------------------------------------------------
__global__ __launch_bounds__(256) void transpose_k(const float* __restrict__ src,
                                                   bf16* __restrict__ dst, int K, int N) {
  int idx = blockIdx.x * 256 + threadIdx.x;
  if (idx >= K * N) return;
  int n = idx / K, k = idx - n * K;
  dst[idx] = __float2bfloat16(src[k * N + n]);
}

// ---------------------------------------------------------------------------
// T1: q gather-transpose: f32 NCHW (one batch) -> bf16 WINDOW-MAJOR qwM[sw][t][c].
// 64hw x 64c LDS tiles; loads coalesced 256B (lanes along hw), stores 128B
// (lanes along c). sw = swoff + (h>>3)*32 + (w>>3), pass-relative.
// ---------------------------------------------------------------------------
__global__ __launch_bounds__(256) void t_winq_k(const float* __restrict__ src,
                                                bf16* __restrict__ dst,
                                                int hw0, int swoff) {
  __shared__ bf16 T[64][66];
  int tile = blockIdx.x;
  int c0 = (tile & 3) << 6;
  int hwb = hw0 + ((tile >> 2) << 6);
  int tid = threadIdx.x;
  {
    int hwl = tid & 63, cb = tid >> 6;
    const float* s = src + (size_t)(c0 + cb) * 65536 + hwb + hwl;
#pragma unroll
    for (int i = 0; i < 16; ++i)
      T[cb + i * 4][hwl] = __float2bfloat16(s[(size_t)i * 4 * 65536]);
  }
  __syncthreads();
  {
    int cl = tid & 63, hb = tid >> 6;
#pragma unroll
    for (int j = 0; j < 16; ++j) {
      int hwl = hb + j * 4;
      int hw = hwb + hwl;
      int h = hw >> 8, w = hw & 255;
      int sw = swoff + ((h >> 3) << 5) + (w >> 3);
      int t = ((h & 7) << 3) + (w & 7);
      dst[((size_t)(sw * 64 + t) << 8) + c0 + cl] = T[cl][hwl];
    }
  }
}

// ---------------------------------------------------------------------------
// T2: kv stripe transpose: f32 NCHW (one batch) -> bf16 NHWC rows starting at
// hw0 (dst pre-offset by caller). Same tile structure as T1, linear dst.
// ---------------------------------------------------------------------------
__global__ __launch_bounds__(256) void t_nhwc_k(const float* __restrict__ src,
                                                bf16* __restrict__ dst, int hw0) {
  __shared__ bf16 T[64][66];
  int tile = blockIdx.x;
  int c0 = (tile & 3) << 6;
  int hwoff = (tile >> 2) << 6;
  int tid = threadIdx.x;
  {
    int hwl = tid & 63, cb = tid >> 6;
    const float* s = src + (size_t)(c0 + cb) * 65536 + hw0 + hwoff + hwl;
#pragma unroll
    for (int i = 0; i < 16; ++i)
      T[cb + i * 4][hwl] = __float2bfloat16(s[(size_t)i * 4 * 65536]);
  }
  __syncthreads();
  {
    int cl = tid & 63, hb = tid >> 6;
#pragma unroll
    for (int j = 0; j < 16; ++j) {
      int hwl = hb + j * 4;
      dst[((size_t)(hwoff + hwl) << 8) + c0 + cl] = T[cl][hwl];
    }
  }
}

// ---------------------------------------------------------------------------
// K1: depthwise 3x3 conv from NHWC bf16 stripe, fused window gather.
// Thread = channel; all loads coalesced (lanes along c, 128B/wave).
// kvbC corresponds to global row h_start; rolling 3-row register buffer.
// ---------------------------------------------------------------------------
__global__ __launch_bounds__(256) void conv_k(const bf16* __restrict__ kvbC,
                                              const float* __restrict__ wdw,
                                              bf16* __restrict__ kvw,
                                              int wid_base, int cw, int psw0,
                                              int h_start) {
  int bid = blockIdx.x;
  int swc = (bid & 7) * (cw >> 3) + (bid >> 3);
  int wid = wid_base + swc;
  int rem = wid & 1023, wh = rem >> 5, ww = rem & 31;
  int h0 = wh * 8, w0 = ww * 8;
  int osw = psw0 + swc;
  int c = threadIdx.x;
  float wr[9];
#pragma unroll
  for (int q = 0; q < 9; ++q) wr[q] = wdw[c * 9 + q];
  const bool wlo = (w0 > 0), whi = (w0 < 248);  // wave-uniform

  float rows[3][10];
  auto load_row = [&](int gh, float* r) {
    if (gh >= 0 && gh < 256) {  // wave-uniform
      const bf16* rp = kvbC + ((size_t)((gh - h_start) * 256 + w0) << 8) + c;
      r[0] = wlo ? __bfloat162float(rp[-256]) : 0.f;
#pragma unroll
      for (int s = 1; s <= 8; ++s) r[s] = __bfloat162float(rp[(s - 1) * 256]);
      r[9] = whi ? __bfloat162float(rp[8 * 256]) : 0.f;
    } else {
#pragma unroll
      for (int e = 0; e < 10; ++e) r[e] = 0.f;
    }
  };

  load_row(h0 - 1, rows[0]);
  load_row(h0, rows[1]);
#pragma unroll
  for (int i = 0; i < 8; ++i) {
    load_row(h0 + i + 1, rows[(i + 2) % 3]);
#pragma unroll
    for (int j = 0; j < 8; ++j) {
      float acc = 0.f;
#pragma unroll
      for (int di = 0; di < 3; ++di) {
        const float* rp = rows[(i + di) % 3];
        acc = __builtin_fmaf(wr[di * 3 + 0], rp[j], acc);
        acc = __builtin_fmaf(wr[di * 3 + 1], rp[j + 1], acc);
        acc = __builtin_fmaf(wr[di * 3 + 2], rp[j + 2], acc);
      }
      kvw[((size_t)(osw * 64 + i * 8 + j) << 8) + c] = __float2bfloat16(acc);
    }
  }
}

// ---------------------------------------------------------------------------
// K2: kv projection GEMM per window: [64x256] @ wkvT -> k_s[t][c], vT_s[d][t].
// Waves 0,1 (k): normal MFMA, D[token][c]. Waves 2,3 (v): SWAPPED operands,
// D[vdim][token] -> direct coalesced vT_s write, no LDS transpose, 1 barrier.
// ---------------------------------------------------------------------------
__global__ __launch_bounds__(256) void kv_gemm_k(const bf16* __restrict__ kvw,
                                                 const bf16* __restrict__ wkvT,
                                                 const float* __restrict__ bkv,
                                                 bf16* __restrict__ k_s,
                                                 bf16* __restrict__ vT_s, int nw) {
  __shared__ __align__(16) bf16 X[64 * 264];
  int bid = blockIdx.x;
  int sw = (bid & 7) * (nw >> 3) + (bid >> 3);
  int tid = threadIdx.x;
  {  // stage A (contiguous copy, vectorized)
    int t = tid >> 2, cb = (tid & 3) * 64;
    const bf16* src = &kvw[((size_t)(sw * 64 + t) << 8) + cb];
    bf16* dst = &X[t * 264 + cb];
    for (int i = 0; i < 8; ++i) *(bf16x8*)&dst[i * 8] = *(const bf16x8*)&src[i * 8];
  }
  __syncthreads();
  int wave = tid >> 6, lane = tid & 63, quad = lane >> 4, l16 = lane & 15;
  int n0 = wave * 128;
  f32x4 zero4 = {0.f, 0.f, 0.f, 0.f};
  f32x4 acc[4][8];
  for (int mt = 0; mt < 4; ++mt)
    for (int nt = 0; nt < 8; ++nt) acc[mt][nt] = zero4;
  if (wave < 2) {
    for (int k0 = 0; k0 < 256; k0 += 32) {
      bf16x8 a[4], bb[8];
      for (int mt = 0; mt < 4; ++mt)
        a[mt] = *(const bf16x8*)&X[(mt * 16 + l16) * 264 + k0 + quad * 8];
      for (int nt = 0; nt < 8; ++nt)
        bb[nt] = *(const bf16x8*)&wkvT[(size_t)(n0 + nt * 16 + l16) * 256 + k0 + quad * 8];
      for (int mt = 0; mt < 4; ++mt)
        for (int nt = 0; nt < 8; ++nt) acc[mt][nt] = MFMA(a[mt], bb[nt], acc[mt][nt]);
    }
  } else {
    for (int k0 = 0; k0 < 256; k0 += 32) {
      bf16x8 a[4], bb[8];
      for (int mt = 0; mt < 4; ++mt)
        a[mt] = *(const bf16x8*)&X[(mt * 16 + l16) * 264 + k0 + quad * 8];
      for (int nt = 0; nt < 8; ++nt)
        bb[nt] = *(const bf16x8*)&wkvT[(size_t)(n0 + nt * 16 + l16) * 256 + k0 + quad * 8];
      for (int mt = 0; mt < 4; ++mt)
        for (int nt = 0; nt < 8; ++nt) acc[mt][nt] = MFMA(bb[nt], a[mt], acc[mt][nt]);
    }
  }
  if (wave < 2) {  // k: D[token][c], token=(quad,r), c=l16
    for (int nt = 0; nt < 8; ++nt) {
      int n = n0 + nt * 16 + l16;
      float bias = bkv[n];
      for (int mt = 0; mt < 4; ++mt) {
        int mb = mt * 16 + quad * 4;
        for (int r = 0; r < 4; ++r)
          k_s[((size_t)(sw * 64 + mb + r) << 8) + n] =
              __float2bfloat16(acc[mt][nt][r] + bias);
      }
    }
  } else {  // v swapped: D[vdim][token], vdim=(quad,r), token=l16
    int base = n0 - 256;
    for (int nt = 0; nt < 8; ++nt) {
      for (int r = 0; r < 4; ++r) {
        int vd = base + nt * 16 + quad * 4 + r;
        float bias = bkv[256 + vd];
        for (int mt = 0; mt < 4; ++mt)
          vT_s[((size_t)(sw * 256 + vd) << 6) + mt * 16 + l16] =
              __float2bfloat16(acc[mt][nt][r] + bias);
      }
    }
  }
}

// ---------------------------------------------------------------------------
// K3: q projection GEMM per window from window-major qwM; q = (x@wq+bq)*SCALE
// Stage is a contiguous 32KB coalesced copy (same as K2's stage A).
// ---------------------------------------------------------------------------
__global__ __launch_bounds__(256) void q_gemm_k(const bf16* __restrict__ qwM,
                                                const bf16* __restrict__ wqT,
                                                const float* __restrict__ bq,
                                                bf16* __restrict__ q_s, int nw) {
  __shared__ __align__(16) bf16 X[64 * 264];
  int bid = blockIdx.x;
  int sw = (bid & 7) * (nw >> 3) + (bid >> 3);
  int tid = threadIdx.x;
  {  // stage (contiguous copy, vectorized)
    int t = tid >> 2, cb = (tid & 3) * 64;
    const bf16* src = &qwM[((size_t)(sw * 64 + t) << 8) + cb];
    bf16* dst = &X[t * 264 + cb];
    for (int i = 0; i < 8; ++i) *(bf16x8*)&dst[i * 8] = *(const bf16x8*)&src[i * 8];
  }
  __syncthreads();
  int wave = tid >> 6, lane = tid & 63, quad = lane >> 4, l16 = lane & 15;
  int n0 = wave * 64;
  f32x4 zero4 = {0.f, 0.f, 0.f, 0.f};
  f32x4 acc[4][4];
  for (int mt = 0; mt < 4; ++mt)
    for (int nt = 0; nt < 4; ++nt) acc[mt][nt] = zero4;
  for (int k0 = 0; k0 < 256; k0 += 32) {
    bf16x8 a[4], bb[4];
    for (int mt = 0; mt < 4; ++mt)
      a[mt] = *(const bf16x8*)&X[(mt * 16 + l16) * 264 + k0 + quad * 8];
    for (int nt = 0; nt < 4; ++nt)
      bb[nt] = *(const bf16x8*)&wqT[(size_t)(n0 + nt * 16 + l16) * 256 + k0 + quad * 8];
    for (int mt = 0; mt < 4; ++mt)
      for (int nt = 0; nt < 4; ++nt) acc[mt][nt] = MFMA(a[mt], bb[nt], acc[mt][nt]);
  }
  const float scale = 0.1767766952966369f;  // 32^-0.5
  for (int nt = 0; nt < 4; ++nt) {
    int n = n0 + nt * 16 + l16;
    float bias = bq[n];
    for (int mt = 0; mt < 4; ++mt) {
      int mb = mt * 16 + quad * 4;
      for (int r = 0; r < 4; ++r)
        q_s[((size_t)(sw * 64 + mb + r) << 8) + n] =
            __float2bfloat16((acc[mt][nt][r] + bias) * scale);
    }
  }
}

// ---------------------------------------------------------------------------
// K4: windowed attention. wave w handles heads {w, w+4}. a_out aliases k_s
// (no __restrict__ on those two!). Safe: each 32-col head block is
// read-then-written by exactly one wave, and hi=0 writes (cols 0..127) are
// disjoint from hi=1 reads (cols 128..255).
// ---------------------------------------------------------------------------
__global__ __launch_bounds__(256) void attn_k(const bf16* __restrict__ q_s,
                                              const bf16* k_s,
                                              const bf16* __restrict__ vT_s,
                                              bf16* a_out, int nw) {
  __shared__ __align__(16) bf16 P[4 * 64 * 72];
  int bid = blockIdx.x;
  int sw = (bid & 7) * (nw >> 3) + (bid >> 3);
  int tid = threadIdx.x, wave = tid >> 6, lane = tid & 63, quad = lane >> 4, l16 = lane & 15;
  const bf16* qw = q_s + ((size_t)sw << 14);
  const bf16* kw = k_s + ((size_t)sw << 14);
  const bf16* vw = vT_s + ((size_t)sw << 14);
  bf16* ow = a_out + ((size_t)sw << 14);
  bf16* Pw = P + wave * 64 * 72;
  f32x4 zero4 = {0.f, 0.f, 0.f, 0.f};
  for (int hi = 0; hi < 2; ++hi) {
    int co = (wave + hi * 4) * 32;  // head channel offset
    f32x4 s[4][4];
    for (int mt = 0; mt < 4; ++mt)
      for (int nt = 0; nt < 4; ++nt) s[mt][nt] = zero4;
    {
      bf16x8 a[4], bb[4];
      for (int mt = 0; mt < 4; ++mt)
        a[mt] = *(const bf16x8*)&qw[(size_t)(mt * 16 + l16) * 256 + co + quad * 8];
      for (int nt = 0; nt < 4; ++nt)
        bb[nt] = *(const bf16x8*)&kw[(size_t)(nt * 16 + l16) * 256 + co + quad * 8];
      for (int mt = 0; mt < 4; ++mt)
        for (int nt = 0; nt < 4; ++nt) s[mt][nt] = MFMA(a[mt], bb[nt], s[mt][nt]);
    }
    float rsum[4][4];
    for (int mt = 0; mt < 4; ++mt) {
      for (int r = 0; r < 4; ++r) {
        float m = s[mt][0][r];
        for (int nt = 1; nt < 4; ++nt) m = fmaxf(m, s[mt][nt][r]);
        m = fmaxf(m, __shfl_xor(m, 1, 64));
        m = fmaxf(m, __shfl_xor(m, 2, 64));
        m = fmaxf(m, __shfl_xor(m, 4, 64));
        m = fmaxf(m, __shfl_xor(m, 8, 64));
        float sum = 0.f;
        for (int nt = 0; nt < 4; ++nt) {
          float e = __expf(s[mt][nt][r] - m);
          s[mt][nt][r] = e;
          sum += e;
        }
        sum += __shfl_xor(sum, 1, 64);
        sum += __shfl_xor(sum, 2, 64);
        sum += __shfl_xor(sum, 4, 64);
        sum += __shfl_xor(sum, 8, 64);
        rsum[mt][r] = sum;
      }
    }
    for (int mt = 0; mt < 4; ++mt)
      for (int nt = 0; nt < 4; ++nt)
        for (int r = 0; r < 4; ++r)
          Pw[(mt * 16 + quad * 4 + r) * 72 + nt * 16 + l16] =
              __float2bfloat16(s[mt][nt][r]);
    __syncthreads();
    f32x4 o[4][2];
    for (int mt = 0; mt < 4; ++mt)
      for (int nt = 0; nt < 2; ++nt) o[mt][nt] = zero4;
    for (int kk = 0; kk < 64; kk += 32) {
      bf16x8 pa[4], vb[2];
      for (int mt = 0; mt < 4; ++mt)
        pa[mt] = *(const bf16x8*)&Pw[(mt * 16 + l16) * 72 + kk + quad * 8];
      for (int nt = 0; nt < 2; ++nt)
        vb[nt] = *(const bf16x8*)&vw[(size_t)(co + nt * 16 + l16) * 64 + kk + quad * 8];
      for (int mt = 0; mt < 4; ++mt)
        for (int nt = 0; nt < 2; ++nt) o[mt][nt] = MFMA(pa[mt], vb[nt], o[mt][nt]);
    }
    for (int mt = 0; mt < 4; ++mt) {
      int mb = mt * 16 + quad * 4;
      for (int nt = 0; nt < 2; ++nt)
        for (int r = 0; r < 4; ++r)
          ow[((size_t)(mb + r) << 8) + co + nt * 16 + l16] =
              __float2bfloat16(o[mt][nt][r] / rsum[mt][r]);
    }
    __syncthreads();
  }
}

// ---------------------------------------------------------------------------
// K5: out projection + window-reverse scatter to NCHW, f32 output.
// ---------------------------------------------------------------------------
__global__ __launch_bounds__(256) void oproj_k(const bf16* __restrict__ a_out,
                                               const bf16* __restrict__ wpT,
                                               const float* __restrict__ bp,
                                               float* __restrict__ out,
                                               int wid_base, int nw) {
  int bid = blockIdx.x;
  int sw = (bid & 7) * (nw >> 3) + (bid >> 3);
  int wid = wid_base + sw;
  int b = wid >> 10, rem = wid & 1023, wh = rem >> 5, ww = rem & 31;
  int h0 = wh * 8, w0 = ww * 8;
  int tid = threadIdx.x, wave = tid >> 6, lane = tid & 63, quad = lane >> 4, l16 = lane & 15;
  const bf16* aw = a_out + ((size_t)sw << 14);
  int n0 = wave * 64;
  f32x4 zero4 = {0.f, 0.f, 0.f, 0.f};
  f32x4 acc[4][4];
  for (int mt = 0; mt < 4; ++mt)
    for (int nt = 0; nt < 4; ++nt) acc[mt][nt] = zero4;
  for (int k0 = 0; k0 < 256; k0 += 32) {
    bf16x8 a[4], bb[4];
    for (int mt = 0; mt < 4; ++mt)
      a[mt] = *(const bf16x8*)&aw[(size_t)(mt * 16 + l16) * 256 + k0 + quad * 8];
    for (int nt = 0; nt < 4; ++nt)
      bb[nt] = *(const bf16x8*)&wpT[(size_t)(n0 + nt * 16 + l16) * 256 + k0 + quad * 8];
    for (int mt = 0; mt < 4; ++mt)
      for (int nt = 0; nt < 4; ++nt) acc[mt][nt] = MFMA(a[mt], bb[nt], acc[mt][nt]);
  }
  for (int nt = 0; nt < 4; ++nt) {
    int n = n0 + nt * 16 + l16;
    float bias = bp[n];
    float* chan = out + ((size_t)(b * 256 + n) << 16);
    for (int mt = 0; mt < 4; ++mt) {
      int row_i = mt * 2 + (quad >> 1);
      int j0 = (quad & 1) * 4;
      f32x4 v4;
      for (int r = 0; r < 4; ++r) v4[r] = acc[mt][nt][r] + bias;
      *(f32x4*)&chan[(size_t)(h0 + row_i) * 256 + w0 + j0] = v4;
    }
  }
}

// ---------------------------------------------------------------------------
extern "C" void kernel_launch(void* const* d_in, const int* in_sizes, int n_in,
                              void* d_out, int out_size, void* d_ws, size_t ws_size,
                              hipStream_t stream) {
  const float* qf  = (const float*)d_in[0];
  const float* kvf = (const float*)d_in[1];
  const float* wdw = (const float*)d_in[2];
  const float* wq  = (const float*)d_in[3];
  const float* bq  = (const float*)d_in[4];
  const float* wkv = (const float*)d_in[5];
  const float* bkv = (const float*)d_in[6];
  const float* wp  = (const float*)d_in[7];
  const float* bp  = (const float*)d_in[8];
  float* out = (float*)d_out;

  bf16* wqT  = (bf16*)d_ws;
  bf16* wkvT = wqT + 256 * 256;
  bf16* wpT  = wkvT + 256 * 512;
  bf16* bufs = wpT + 256 * 256;
  const size_t welems = 65536 + 131072 + 65536;

  int passes = 1;
  while (passes < 32) {
    size_t nw_ = 2048 / passes;
    size_t elems = welems + 5 * nw_ * 16384 + 4 * 65536;
    if (elems * 2 <= ws_size) break;
    passes <<= 1;
  }
  int nw = 2048 / passes;
  size_t sz = (size_t)nw * 16384;
  bf16* qwM = bufs;                     // window-major staged q (bf16)
  bf16* kvb = qwM + sz;                 // NHWC kv stripe (+halo rows)
  bf16* R0  = kvb + sz + 4 * 65536;     // kvw, then q_s
  bf16* R1  = R0 + sz;                  // k_s, then attn-out
  bf16* R2  = R1 + sz;                  // vT_s

  transpose_k<<<256, 256, 0, stream>>>(wq, wqT, 256, 256);
  transpose_k<<<512, 256, 0, stream>>>(wkv, wkvT, 256, 512);
  transpose_k<<<256, 256, 0, stream>>>(wp, wpT, 256, 256);

  for (int p = 0; p < passes; ++p) {
    int wbP = p * nw;
    int nchunks = (nw > 1024) ? 2 : 1;
    int cw = nw / nchunks;  // <= 1024, single batch per chunk
    for (int ch = 0; ch < nchunks; ++ch) {
      int wbC = wbP + ch * cw;
      int b = wbC >> 10;
      int h0 = ((wbC & 1023) >> 5) * 8;
      int nh = (cw >> 5) * 8;
      int psw0 = ch * cw;
      const float* qsrc = qf + ((size_t)b << 24);
      const float* ksrc = kvf + ((size_t)b << 24);
      // q: direct window-major gather-transpose
      t_winq_k<<<cw * 4, 256, 0, stream>>>(qsrc, qwM, h0 * 256, b * 1024 - wbP);
      // kv: NHWC stripe with halo rows
      int gh_lo = h0 > 0 ? h0 - 1 : 0;
      int gh_hi = (h0 + nh + 1 < 256) ? h0 + nh + 1 : 256;
      int rows = gh_hi - gh_lo;
      int h_start = h0 - 1;
      bf16* kvbC = kvb + (size_t)ch * (size_t)(nh + 2) * 65536;
      bf16* tdst = kvbC + (size_t)(gh_lo - h_start) * 65536;
      t_nhwc_k<<<rows * 16, 256, 0, stream>>>(ksrc, tdst, gh_lo * 256);
      conv_k<<<cw, 256, 0, stream>>>(kvbC, wdw, R0, wbC, cw, psw0, h_start);
    }
    kv_gemm_k<<<nw, 256, 0, stream>>>(R0, wkvT, bkv, R1, R2, nw);
    q_gemm_k<<<nw, 256, 0, stream>>>(qwM, wqT, bq, R0, nw);
    attn_k<<<nw, 256, 0, stream>>>(R0, R1, R2, R1, nw);
    oproj_k<<<nw, 256, 0, stream>>>(R1, wpT, bp, out, wbP, nw);
  }
}